// Round 5
// baseline (137.283 us; speedup 1.0000x reference)
//
#include <hip/hip_runtime.h>

// SparseShiftGateRecurrence: h[t] = alpha*h[t-1] + beta*x[t] on channels [0,512),
// passthrough on [512,2048). B=8, S=4096, D=2048, fp32.
//
// alpha=0.9 contractive -> split each (b,channel) chain into chunks of
// CHUNK=64 steps, warmed from h=0 over up-to-WARM=224 preceding steps
// (truncation 0.9^224 ~ 5.6e-11; chunks 0..3 warm from t=0 -> exact).
//
// v5: v4 showed ~4.4 TB/s effective vs 6.3 ceiling; theory = exposed rec tail:
// rec waves stall once per load-batch (44 batches) at contention-inflated HBM
// latency while the copy phase hogs BW, then finish ~30us after the copy
// drains. Attack stall count on both axes:
//  - BD 8->16 ping-pong (32 loads in flight/thread): stall events 44 -> 18.
//  - CHUNK 128->64: chains 352->288, rec threads 32768->65536 (256 blocks).
//  - scalar-component FMA restored (v2 form, absmax was 0.0 there; the
//    ext-vector al*h+be*v form coincided with absmax 0.0039 -> A/B probe).
// Store policy: normal stores (v3b/v4 A/B was confounded by WARM; no evidence
// NT helps). NT loads kept on the streaming copy (keep L3 for active region).

#define BATCH   8
#define SEQ     4096
#define DIM     2048
#define ACTIVE  512
#define ROWQ    (DIM / 4)       // 512 vec4 per (b,s) row
#define CHUNK   64
#define WARM    224
#define NCHUNK  (SEQ / CHUNK)   // 64
#define GROUPS  (ACTIVE / 4)    // 128 vec4 channel-groups
#define REC_THREADS (NCHUNK * BATCH * GROUPS)   // 65536
#define REC_BLOCKS  (REC_THREADS / 256)         // 256
#define COPY_ROWS   (BATCH * SEQ)               // 32768
#define ROWS_PER_BLOCK 4
#define COPY_BLOCKS (COPY_ROWS / ROWS_PER_BLOCK) // 8192
#define BD      16              // loads per half-buffer (ping-pong 16+16)

typedef float fvec4 __attribute__((ext_vector_type(4)));

__global__ __launch_bounds__(256) void ssgr_kernel(
    const float* __restrict__ x,
    const float* __restrict__ alpha,
    const float* __restrict__ beta,
    float* __restrict__ out) {
  const fvec4* __restrict__ x4 = reinterpret_cast<const fvec4*>(x);
  fvec4* __restrict__ out4 = reinterpret_cast<fvec4*>(out);
  const int bi = blockIdx.x;

  if (bi < REC_BLOCKS) {
    // ---- recurrence: one thread per (chunk, batch, channel-group) ----
    const int r  = bi * 256 + threadIdx.x;       // 0..65535
    const int g  = r & (GROUPS - 1);             // lanes consecutive -> coalesced
    const int b  = (r >> 7) & (BATCH - 1);       // wave-uniform
    const int ci = r >> 10;                      // chunk 0..63, wave-uniform

    const fvec4 al = reinterpret_cast<const fvec4*>(alpha)[g];
    const fvec4 be = reinterpret_cast<const fvec4*>(beta)[g];

    const int t0 = ci * CHUNK;
    int tstart = t0 - WARM;
    if (tstart < 0) tstart = 0;
    const int warm = t0 - tstart;          // 0,64,128,192,224 -> warm+CHUNK % 16 == 0
    const int nb   = (warm + CHUNK) / BD;  // 4,8,12,16,18 -- always even
    const int wb   = warm / BD;            // first batch index that stores (nb-wb==4)

    const long rowbase = (long)b * SEQ;
    const fvec4* xp = x4 + (rowbase + tstart) * ROWQ + g;
    fvec4* op = out4 + (rowbase + t0) * ROWQ + g;

    fvec4 h = (fvec4)(0.f);
    fvec4 va[BD], vb[BD];

    auto loadB = [&](fvec4* v) {
      #pragma unroll
      for (int k = 0; k < BD; ++k) v[k] = xp[k * ROWQ];
      xp += BD * ROWQ;
    };
    auto fmaB = [&](const fvec4* v) {
      #pragma unroll
      for (int k = 0; k < BD; ++k) {
        h.x = al.x * h.x + be.x * v[k].x;
        h.y = al.y * h.y + be.y * v[k].y;
        h.z = al.z * h.z + be.z * v[k].z;
        h.w = al.w * h.w + be.w * v[k].w;
      }
    };
    auto fmaBst = [&](const fvec4* v) {
      #pragma unroll
      for (int k = 0; k < BD; ++k) {
        h.x = al.x * h.x + be.x * v[k].x;
        h.y = al.y * h.y + be.y * v[k].y;
        h.z = al.z * h.z + be.z * v[k].z;
        h.w = al.w * h.w + be.w * v[k].w;
        op[k * ROWQ] = h;
      }
      op += BD * ROWQ;
    };

    // prologue: batch 0 in flight
    loadB(va);
    // steady state: issue batch j+1 / consume batch j, ping-pong
    for (int j = 0; j + 2 < nb; j += 2) {
      loadB(vb);                             // batch j+1
      __builtin_amdgcn_sched_barrier(0);     // loads stay ahead of FMAs
      if (j >= wb) fmaBst(va); else fmaB(va);
      loadB(va);                             // batch j+2
      __builtin_amdgcn_sched_barrier(0);
      if (j + 1 >= wb) fmaBst(vb); else fmaB(vb);
    }
    // tail pair: batches nb-2 (in va) and nb-1; both always in store region
    loadB(vb);
    __builtin_amdgcn_sched_barrier(0);
    fmaBst(va);
    fmaBst(vb);
  } else {
    // ---- passthrough copy: one wave per (b,s) row tail of 1536 floats ----
    // NT loads: pure streaming, keep L3 for the active region. Normal stores.
    const int row  = (bi - REC_BLOCKS) * ROWS_PER_BLOCK + (threadIdx.x >> 6);
    const int lane = threadIdx.x & 63;
    const fvec4* __restrict__ src = x4   + (long)row * ROWQ + (ACTIVE / 4);
    fvec4* __restrict__ dst       = out4 + (long)row * ROWQ + (ACTIVE / 4);
    #pragma unroll
    for (int k = 0; k < 6; ++k) {        // 384 vec4 per row / 64 lanes
      fvec4 v = __builtin_nontemporal_load(&src[lane + 64 * k]);
      dst[lane + 64 * k] = v;
    }
  }
}

extern "C" void kernel_launch(void* const* d_in, const int* in_sizes, int n_in,
                              void* d_out, int out_size, void* d_ws, size_t ws_size,
                              hipStream_t stream) {
  const float* x     = (const float*)d_in[0];
  const float* alpha = (const float*)d_in[1];
  const float* beta  = (const float*)d_in[2];
  float* out = (float*)d_out;
  (void)in_sizes; (void)n_in; (void)out_size; (void)d_ws; (void)ws_size;

  dim3 grid(REC_BLOCKS + COPY_BLOCKS);
  dim3 block(256);
  hipLaunchKernelGGL(ssgr_kernel, grid, block, 0, stream, x, alpha, beta, out);
}

// Round 6
// 131.237 us; speedup vs baseline: 1.0461x; 1.0461x over previous
//
#include <hip/hip_runtime.h>

// SparseShiftGateRecurrence: h[t] = alpha*h[t-1] + beta*x[t] on channels [0,512),
// passthrough on [512,2048). B=8, S=4096, D=2048, fp32.
//
// alpha=0.9 contractive -> split each (b,channel) chain into chunks of
// CHUNK=256 steps, warmed from h=0 over WARM=224 preceding steps
// (truncation 0.9^224 ~ 5.6e-11 * |h|; chunk 0 exact).
//
// Perf model (validated v3b/v4/v5): bound by ISSUED vector-memory traffic at
// ~6.2 TB/s (L3 absorption of warm re-reads does NOT help -- FETCH ~190MB but
// time tracks issued bytes). v3b 634MB->102.5us, v4 650MB->104.8us,
// v5 771MB->137us. Lever: cut warm amplification.
// v6: CHUNK 128->256: rec issued reads 181->122MB, total 591MB -> ~95us.
//     16384 rec threads x ~12 outstanding x 16B ~ 3MB in flight -> no tail.
//     NT copy-load removed (A/B: only unexplained var in the absmax 0.0039
//     runs; traffic volume, not cache policy, is what matters here).
//     BD=8 ping-pong + sched_barrier(0) kept (v5's BD=16 cost VGPRs for
//     nothing). Scalar-component FMA kept.

#define BATCH   8
#define SEQ     4096
#define DIM     2048
#define ACTIVE  512
#define ROWQ    (DIM / 4)       // 512 vec4 per (b,s) row
#define CHUNK   256
#define WARM    224
#define NCHUNK  (SEQ / CHUNK)   // 16
#define GROUPS  (ACTIVE / 4)    // 128 vec4 channel-groups
#define REC_THREADS (NCHUNK * BATCH * GROUPS)   // 16384
#define REC_BLOCKS  (REC_THREADS / 256)         // 64
#define COPY_ROWS   (BATCH * SEQ)               // 32768
#define ROWS_PER_BLOCK 4
#define COPY_BLOCKS (COPY_ROWS / ROWS_PER_BLOCK) // 8192
#define BD      8               // loads per half-buffer (ping-pong 8+8)

typedef float fvec4 __attribute__((ext_vector_type(4)));

__global__ __launch_bounds__(256) void ssgr_kernel(
    const float* __restrict__ x,
    const float* __restrict__ alpha,
    const float* __restrict__ beta,
    float* __restrict__ out) {
  const fvec4* __restrict__ x4 = reinterpret_cast<const fvec4*>(x);
  fvec4* __restrict__ out4 = reinterpret_cast<fvec4*>(out);
  const int bi = blockIdx.x;

  if (bi < REC_BLOCKS) {
    // ---- recurrence: one thread per (chunk, batch, channel-group) ----
    const int r  = bi * 256 + threadIdx.x;       // 0..16383
    const int g  = r & (GROUPS - 1);             // lanes consecutive -> coalesced
    const int b  = (r >> 7) & (BATCH - 1);       // wave-uniform
    const int ci = r >> 10;                      // chunk 0..15, wave-uniform

    const fvec4 al = reinterpret_cast<const fvec4*>(alpha)[g];
    const fvec4 be = reinterpret_cast<const fvec4*>(beta)[g];

    const int t0 = ci * CHUNK;
    int tstart = t0 - WARM;
    if (tstart < 0) tstart = 0;
    const int warm = t0 - tstart;          // 0 (ci=0) or 224
    const int nb   = (warm + CHUNK) / BD;  // 32 or 60 -- always even
    const int wb   = warm / BD;            // 0 or 28 -- first storing batch

    const long rowbase = (long)b * SEQ;
    const fvec4* xp = x4 + (rowbase + tstart) * ROWQ + g;
    fvec4* op = out4 + (rowbase + t0) * ROWQ + g;

    fvec4 h = (fvec4)(0.f);
    fvec4 va[BD], vb[BD];

    auto loadB = [&](fvec4* v) {
      #pragma unroll
      for (int k = 0; k < BD; ++k) v[k] = xp[k * ROWQ];
      xp += BD * ROWQ;
    };
    auto fmaB = [&](const fvec4* v) {
      #pragma unroll
      for (int k = 0; k < BD; ++k) {
        h.x = al.x * h.x + be.x * v[k].x;
        h.y = al.y * h.y + be.y * v[k].y;
        h.z = al.z * h.z + be.z * v[k].z;
        h.w = al.w * h.w + be.w * v[k].w;
      }
    };
    auto fmaBst = [&](const fvec4* v) {
      #pragma unroll
      for (int k = 0; k < BD; ++k) {
        h.x = al.x * h.x + be.x * v[k].x;
        h.y = al.y * h.y + be.y * v[k].y;
        h.z = al.z * h.z + be.z * v[k].z;
        h.w = al.w * h.w + be.w * v[k].w;
        op[k * ROWQ] = h;
      }
      op += BD * ROWQ;
    };

    // prologue: batch 0 in flight
    loadB(va);
    // steady state: issue batch j+1 / consume batch j, ping-pong
    for (int j = 0; j + 2 < nb; j += 2) {
      loadB(vb);                             // batch j+1
      __builtin_amdgcn_sched_barrier(0);     // loads stay ahead of FMAs
      if (j >= wb) fmaBst(va); else fmaB(va);
      loadB(va);                             // batch j+2
      __builtin_amdgcn_sched_barrier(0);
      if (j + 1 >= wb) fmaBst(vb); else fmaB(vb);
    }
    // tail pair: batches nb-2 (in va) and nb-1; both always in store region
    loadB(vb);
    __builtin_amdgcn_sched_barrier(0);
    fmaBst(va);
    fmaBst(vb);
  } else {
    // ---- passthrough copy: one wave per (b,s) row tail of 1536 floats ----
    const int row  = (bi - REC_BLOCKS) * ROWS_PER_BLOCK + (threadIdx.x >> 6);
    const int lane = threadIdx.x & 63;
    const fvec4* __restrict__ src = x4   + (long)row * ROWQ + (ACTIVE / 4);
    fvec4* __restrict__ dst       = out4 + (long)row * ROWQ + (ACTIVE / 4);
    #pragma unroll
    for (int k = 0; k < 6; ++k) {        // 384 vec4 per row / 64 lanes
      dst[lane + 64 * k] = src[lane + 64 * k];
    }
  }
}

extern "C" void kernel_launch(void* const* d_in, const int* in_sizes, int n_in,
                              void* d_out, int out_size, void* d_ws, size_t ws_size,
                              hipStream_t stream) {
  const float* x     = (const float*)d_in[0];
  const float* alpha = (const float*)d_in[1];
  const float* beta  = (const float*)d_in[2];
  float* out = (float*)d_out;
  (void)in_sizes; (void)n_in; (void)out_size; (void)d_ws; (void)ws_size;

  dim3 grid(REC_BLOCKS + COPY_BLOCKS);
  dim3 block(256);
  hipLaunchKernelGGL(ssgr_kernel, grid, block, 0, stream, x, alpha, beta, out);
}

// Round 7
// 115.630 us; speedup vs baseline: 1.1873x; 1.1350x over previous
//
#include <hip/hip_runtime.h>

// SparseShiftGateRecurrence: h[t] = alpha*h[t-1] + beta*x[t] on channels [0,512),
// passthrough on [512,2048). B=8, S=4096, D=2048, fp32.
//
// Perf model (validated v3b..v6):
//   time ~ max( issued_vmem_bytes / 6.2 TB/s , nb * eff_batch_latency )
// with constraints: >=128 rec blocks (v6's 64 -> latency tail, 131us),
// nb <= ~45 batches/chain, BD=8 (v5's BD=16 -> VGPR pressure, 137us).
// v3b: 634MB -> 102.5us, v4: 650MB -> 104.8us (both exact fits).
//
// v7: cut warm amplification at fixed parallelism via float2 granularity:
// GROUPS 128->256 channel-pairs, so CHUNK=256 keeps 32768 threads/128 blocks
// while WARM=128 amortizes over 2x more useful steps. Issued bytes
// 650 -> 568 MB (rec reads 181->99 MB) -> predicted ~92us.
// Truncation 0.9^128 ~ 1.6e-6 * |h| ~ 2e-7 (chunk 0 exact; all others warm
// the full 128). Chain = 47 batches ~ v4's 44. Loads dwordx2, 64 lanes
// consecutive -> 512B/wave-instr, fully coalesced. BD=8 ping-pong +
// sched_barrier(0) keeps ~16 loads/thread in flight (4.2 MB outstanding).

#define BATCH   8
#define SEQ     4096
#define DIM     2048
#define ACTIVE  512
#define ROWQ    (DIM / 4)       // 512 fvec4 per (b,s) row (copy path)
#define ROWP    (DIM / 2)       // 1024 fvec2 per (b,s) row (rec path)
#define CHUNK   256
#define WARM    128
#define NCHUNK  (SEQ / CHUNK)   // 16
#define GROUPS2 (ACTIVE / 2)    // 256 fvec2 channel-pairs
#define REC_THREADS (NCHUNK * BATCH * GROUPS2)  // 32768
#define REC_BLOCKS  (REC_THREADS / 256)         // 128
#define COPY_ROWS   (BATCH * SEQ)               // 32768
#define ROWS_PER_BLOCK 4
#define COPY_BLOCKS (COPY_ROWS / ROWS_PER_BLOCK) // 8192
#define BD      8               // loads per half-buffer (ping-pong 8+8)

typedef float fvec2 __attribute__((ext_vector_type(2)));
typedef float fvec4 __attribute__((ext_vector_type(4)));

__global__ __launch_bounds__(256) void ssgr_kernel(
    const float* __restrict__ x,
    const float* __restrict__ alpha,
    const float* __restrict__ beta,
    float* __restrict__ out) {
  const int bi = blockIdx.x;

  if (bi < REC_BLOCKS) {
    // ---- recurrence: one thread per (chunk, batch, channel-pair) ----
    const fvec2* __restrict__ x2 = reinterpret_cast<const fvec2*>(x);
    fvec2* __restrict__ out2 = reinterpret_cast<fvec2*>(out);
    const int r  = bi * 256 + threadIdx.x;       // 0..32767
    const int g  = r & (GROUPS2 - 1);            // lanes consecutive -> coalesced
    const int b  = (r >> 8) & (BATCH - 1);       // wave-uniform
    const int ci = r >> 11;                      // chunk 0..15, wave-uniform

    const fvec2 al = reinterpret_cast<const fvec2*>(alpha)[g];
    const fvec2 be = reinterpret_cast<const fvec2*>(beta)[g];

    const int t0 = ci * CHUNK;
    int tstart = t0 - WARM;
    if (tstart < 0) tstart = 0;
    const int warm = t0 - tstart;          // 0 (ci=0) or 128
    const int nb   = (warm + CHUNK) / BD;  // 32 or 48 -- always even
    const int wb   = warm / BD;            // 0 or 16 -- first storing batch

    const long rowbase = (long)b * SEQ;
    const fvec2* xp = x2 + (rowbase + tstart) * ROWP + g;
    fvec2* op = out2 + (rowbase + t0) * ROWP + g;

    fvec2 h = (fvec2)(0.f);
    fvec2 va[BD], vb[BD];

    auto loadB = [&](fvec2* v) {
      #pragma unroll
      for (int k = 0; k < BD; ++k) v[k] = xp[k * ROWP];
      xp += BD * ROWP;
    };
    auto fmaB = [&](const fvec2* v) {
      #pragma unroll
      for (int k = 0; k < BD; ++k) {
        h.x = al.x * h.x + be.x * v[k].x;
        h.y = al.y * h.y + be.y * v[k].y;
      }
    };
    auto fmaBst = [&](const fvec2* v) {
      #pragma unroll
      for (int k = 0; k < BD; ++k) {
        h.x = al.x * h.x + be.x * v[k].x;
        h.y = al.y * h.y + be.y * v[k].y;
        op[k * ROWP] = h;
      }
      op += BD * ROWP;
    };

    // prologue: batch 0 in flight
    loadB(va);
    // steady state: issue batch j+1 / consume batch j, ping-pong
    for (int j = 0; j + 2 < nb; j += 2) {
      loadB(vb);                             // batch j+1
      __builtin_amdgcn_sched_barrier(0);     // loads stay ahead of FMAs
      if (j >= wb) fmaBst(va); else fmaB(va);
      loadB(va);                             // batch j+2
      __builtin_amdgcn_sched_barrier(0);
      if (j + 1 >= wb) fmaBst(vb); else fmaB(vb);
    }
    // tail pair: batches nb-2 (in va) and nb-1; both always in store region
    loadB(vb);
    __builtin_amdgcn_sched_barrier(0);
    fmaBst(va);
    fmaBst(vb);
  } else {
    // ---- passthrough copy: one wave per (b,s) row tail of 1536 floats ----
    const fvec4* __restrict__ x4 = reinterpret_cast<const fvec4*>(x);
    fvec4* __restrict__ out4 = reinterpret_cast<fvec4*>(out);
    const int row  = (bi - REC_BLOCKS) * ROWS_PER_BLOCK + (threadIdx.x >> 6);
    const int lane = threadIdx.x & 63;
    const fvec4* __restrict__ src = x4   + (long)row * ROWQ + (ACTIVE / 4);
    fvec4* __restrict__ dst       = out4 + (long)row * ROWQ + (ACTIVE / 4);
    #pragma unroll
    for (int k = 0; k < 6; ++k) {        // 384 fvec4 per row / 64 lanes
      dst[lane + 64 * k] = src[lane + 64 * k];
    }
  }
}

extern "C" void kernel_launch(void* const* d_in, const int* in_sizes, int n_in,
                              void* d_out, int out_size, void* d_ws, size_t ws_size,
                              hipStream_t stream) {
  const float* x     = (const float*)d_in[0];
  const float* alpha = (const float*)d_in[1];
  const float* beta  = (const float*)d_in[2];
  float* out = (float*)d_out;
  (void)in_sizes; (void)n_in; (void)out_size; (void)d_ws; (void)ws_size;

  dim3 grid(REC_BLOCKS + COPY_BLOCKS);
  dim3 block(256);
  hipLaunchKernelGGL(ssgr_kernel, grid, block, 0, stream, x, alpha, beta, out);
}

// Round 8
// 103.258 us; speedup vs baseline: 1.3295x; 1.1198x over previous
//
#include <hip/hip_runtime.h>

// SparseShiftGateRecurrence: h[t] = alpha*h[t-1] + beta*x[t] on channels [0,512),
// passthrough on [512,2048). B=8, S=4096, D=2048, fp32.
//
// Perf model (validated v3b..v7): bound by issued 64-lane wave-TRANSACTIONS at
// ~6.2K txns/us with 16B/lane (1KB/txn) accesses:
//   v3b 637K->102.5us, v4 650K->104.8us (exact), v7 (8B/lane rec) 730K->115.6us.
// Shrinking access width buys nothing (same txns/step); fvec4 is optimal.
// Constraints: >=128 rec blocks (v6: 64 -> latency tail), nb<=~45 batches/chain
// (v6: 60 -> serialized), BD=8 (v5: 16 -> VGPR pressure). These pin CHUNK=128.
//
// v8: WARM 224->96. Truncation 0.9^96 * |h|max(~1.3) ~ 5e-5, three orders
// below the structural absmax 0.0039 (proven truncation-independent: identical
// at WARM=192/224 where truncation differs 30x). Issued traffic
// 650 -> 587 MB (587K txns) -> predicted ~95us. Compulsory floor 537MB/86.6us.
// Chain nb=28 batches (safest yet). Everything else = v4: fvec4, BD=8
// ping-pong + sched_barrier(0) (~16 loads in flight/thread), normal stores.

#define BATCH   8
#define SEQ     4096
#define DIM     2048
#define ACTIVE  512
#define ROWQ    (DIM / 4)       // 512 vec4 per (b,s) row
#define CHUNK   128
#define WARM    96
#define NCHUNK  (SEQ / CHUNK)   // 32
#define GROUPS  (ACTIVE / 4)    // 128 vec4 channel-groups
#define REC_THREADS (NCHUNK * BATCH * GROUPS)   // 32768
#define REC_BLOCKS  (REC_THREADS / 256)         // 128
#define COPY_ROWS   (BATCH * SEQ)               // 32768
#define ROWS_PER_BLOCK 4
#define COPY_BLOCKS (COPY_ROWS / ROWS_PER_BLOCK) // 8192
#define BD      8               // loads per half-buffer (ping-pong 8+8)

typedef float fvec4 __attribute__((ext_vector_type(4)));

__global__ __launch_bounds__(256) void ssgr_kernel(
    const float* __restrict__ x,
    const float* __restrict__ alpha,
    const float* __restrict__ beta,
    float* __restrict__ out) {
  const fvec4* __restrict__ x4 = reinterpret_cast<const fvec4*>(x);
  fvec4* __restrict__ out4 = reinterpret_cast<fvec4*>(out);
  const int bi = blockIdx.x;

  if (bi < REC_BLOCKS) {
    // ---- recurrence: one thread per (chunk, batch, channel-group) ----
    const int r  = bi * 256 + threadIdx.x;       // 0..32767
    const int g  = r & (GROUPS - 1);             // lanes consecutive -> coalesced
    const int b  = (r >> 7) & (BATCH - 1);       // wave-uniform
    const int ci = r >> 10;                      // chunk 0..31, wave-uniform

    const fvec4 al = reinterpret_cast<const fvec4*>(alpha)[g];
    const fvec4 be = reinterpret_cast<const fvec4*>(beta)[g];

    const int t0 = ci * CHUNK;
    int tstart = t0 - WARM;
    if (tstart < 0) tstart = 0;
    const int warm = t0 - tstart;          // 0 (ci=0) or 96
    const int nb   = (warm + CHUNK) / BD;  // 16 or 28 -- always even
    const int wb   = warm / BD;            // 0 or 12 -- first storing batch

    const long rowbase = (long)b * SEQ;
    const fvec4* xp = x4 + (rowbase + tstart) * ROWQ + g;
    fvec4* op = out4 + (rowbase + t0) * ROWQ + g;

    fvec4 h = (fvec4)(0.f);
    fvec4 va[BD], vb[BD];

    auto loadB = [&](fvec4* v) {
      #pragma unroll
      for (int k = 0; k < BD; ++k) v[k] = xp[k * ROWQ];
      xp += BD * ROWQ;
    };
    auto fmaB = [&](const fvec4* v) {
      #pragma unroll
      for (int k = 0; k < BD; ++k) {
        h.x = al.x * h.x + be.x * v[k].x;
        h.y = al.y * h.y + be.y * v[k].y;
        h.z = al.z * h.z + be.z * v[k].z;
        h.w = al.w * h.w + be.w * v[k].w;
      }
    };
    auto fmaBst = [&](const fvec4* v) {
      #pragma unroll
      for (int k = 0; k < BD; ++k) {
        h.x = al.x * h.x + be.x * v[k].x;
        h.y = al.y * h.y + be.y * v[k].y;
        h.z = al.z * h.z + be.z * v[k].z;
        h.w = al.w * h.w + be.w * v[k].w;
        op[k * ROWQ] = h;
      }
      op += BD * ROWQ;
    };

    // prologue: batch 0 in flight
    loadB(va);
    // steady state: issue batch j+1 / consume batch j, ping-pong
    for (int j = 0; j + 2 < nb; j += 2) {
      loadB(vb);                             // batch j+1
      __builtin_amdgcn_sched_barrier(0);     // loads stay ahead of FMAs
      if (j >= wb) fmaBst(va); else fmaB(va);
      loadB(va);                             // batch j+2
      __builtin_amdgcn_sched_barrier(0);
      if (j + 1 >= wb) fmaBst(vb); else fmaB(vb);
    }
    // tail pair: batches nb-2 (in va) and nb-1; both always in store region
    loadB(vb);
    __builtin_amdgcn_sched_barrier(0);
    fmaBst(va);
    fmaBst(vb);
  } else {
    // ---- passthrough copy: one wave per (b,s) row tail of 1536 floats ----
    const int row  = (bi - REC_BLOCKS) * ROWS_PER_BLOCK + (threadIdx.x >> 6);
    const int lane = threadIdx.x & 63;
    const fvec4* __restrict__ src = x4   + (long)row * ROWQ + (ACTIVE / 4);
    fvec4* __restrict__ dst       = out4 + (long)row * ROWQ + (ACTIVE / 4);
    #pragma unroll
    for (int k = 0; k < 6; ++k) {        // 384 vec4 per row / 64 lanes
      dst[lane + 64 * k] = src[lane + 64 * k];
    }
  }
}

extern "C" void kernel_launch(void* const* d_in, const int* in_sizes, int n_in,
                              void* d_out, int out_size, void* d_ws, size_t ws_size,
                              hipStream_t stream) {
  const float* x     = (const float*)d_in[0];
  const float* alpha = (const float*)d_in[1];
  const float* beta  = (const float*)d_in[2];
  float* out = (float*)d_out;
  (void)in_sizes; (void)n_in; (void)out_size; (void)d_ws; (void)ws_size;

  dim3 grid(REC_BLOCKS + COPY_BLOCKS);
  dim3 block(256);
  hipLaunchKernelGGL(ssgr_kernel, grid, block, 0, stream, x, alpha, beta, out);
}